// Round 4
// baseline (221.810 us; speedup 1.0000x reference)
//
#include <hip/hip_runtime.h>
#include <hip/hip_cooperative_groups.h>

namespace cg = cooperative_groups;

// B=32, L=512, N=128, IN=16, OUT=10
// Primary path: ONE cooperative kernel, grid=256 x 512 threads (1 block/CU).
// Stages separated by grid.sync():
//   1: h = relu(relu(x@W1+b1)@W2+b2)            (B*L, 64)   64 rows/block
//   2: h_agg = max_l h*tree ; m = relu(@W3+b3)  (B, N*16)   2 units/block
//   3: part = split-K(16) of m@W4               (B, 16, 64) 2 units/block
//   4: y=relu(sum+b4); BN batch stats; @W5+b5   (B, 10)     block 0
// Fallback path (if cooperative launch fails): proven R2 4-kernel pipeline.

__global__ __launch_bounds__(512, 2) void k_fused(
    const float* __restrict__ x, const float* __restrict__ tree,
    const float* __restrict__ W1, const float* __restrict__ b1,
    const float* __restrict__ W2, const float* __restrict__ b2,
    const float* __restrict__ W3, const float* __restrict__ b3,
    const float* __restrict__ W4, const float* __restrict__ b4,
    const float* __restrict__ gamma, const float* __restrict__ beta,
    const float* __restrict__ W5, const float* __restrict__ b5,
    float* __restrict__ out, float* __restrict__ h,
    float* __restrict__ m, float* __restrict__ part)
{
    cg::grid_group grid = cg::this_grid();
    const int tid = threadIdx.x;
    const int bid = blockIdx.x;

    __shared__ float sx[1024];                      // 64 rows x 16 of x
    __shared__ float sh1[2][8][32];                 // layer-1 dbuf
    __shared__ __align__(16) float tl[512][8];      // transposed tree tile
    __shared__ float sred2[8][8][64];
    __shared__ float sagg[8][64];
    __shared__ float sm3[128];
    __shared__ float sred3[8][64];
    __shared__ float sy[2048];
    __shared__ float sstat[3][64];

    // ================= stage 1: micro MLP (64 rows/block) =================
    {
        const int r = tid >> 6;                     // 0..7
        const int c = tid & 63;
        const int row0 = bid * 64;
        sx[tid]       = x[(size_t)row0 * 16 + tid];
        sx[tid + 512] = x[(size_t)row0 * 16 + 512 + tid];
        float w2r[32];
        #pragma unroll
        for (int j = 0; j < 32; ++j) w2r[j] = W2[j * 64 + c];
        __syncthreads();
        #pragma unroll
        for (int it = 0; it < 8; ++it) {
            int rr = it * 8 + r;
            if (c < 32) {
                float a = b1[c];
                #pragma unroll
                for (int i = 0; i < 16; ++i) a += sx[rr * 16 + i] * W1[i * 32 + c];
                sh1[it & 1][r][c] = fmaxf(a, 0.f);
            }
            __syncthreads();                        // dbuf: 1 barrier/iter
            float a = b2[c];
            #pragma unroll
            for (int j = 0; j < 32; ++j) a += sh1[it & 1][r][j] * w2r[j];
            h[(size_t)(row0 + rr) * 64 + c] = fmaxf(a, 0.f);
        }
    }
    __threadfence();
    grid.sync();

    // ========== stage 2: tree max-agg + macro (2 units, same ng) ==========
    {
        const int u0 = bid * 2;                     // units u0, u0+1 share ng
        const int ng = u0 >> 5;                     // 0..15 (node group of 8)
        // conflict-free staging: tl[l][n] at linear addr idx = l*8+n
        for (int idx = tid; idx < 4096; idx += 512) {
            int n = idx & 7, l = idx >> 3;
            tl[l][n] = tree[(size_t)(ng * 8 + n) * 512 + l];
        }
        __syncthreads();
        const int g = tid >> 6;                     // leaf phase 0..7
        const int c = tid & 63;
        #pragma unroll
        for (int ub = 0; ub < 2; ++ub) {
            const int b = (u0 + ub) & 31;
            float acc[8];
            #pragma unroll
            for (int j = 0; j < 8; ++j) acc[j] = 0.f;   // products >=0: exact
            const float* hb = h + (size_t)b * 32768 + c;
            #pragma unroll 4
            for (int l = g; l < 512; l += 8) {
                float hv = hb[(size_t)l * 64];
                float4 t0 = *(const float4*)&tl[l][0];  // broadcast reads
                float4 t1 = *(const float4*)&tl[l][4];
                acc[0] = fmaxf(acc[0], hv * t0.x);
                acc[1] = fmaxf(acc[1], hv * t0.y);
                acc[2] = fmaxf(acc[2], hv * t0.z);
                acc[3] = fmaxf(acc[3], hv * t0.w);
                acc[4] = fmaxf(acc[4], hv * t1.x);
                acc[5] = fmaxf(acc[5], hv * t1.y);
                acc[6] = fmaxf(acc[6], hv * t1.z);
                acc[7] = fmaxf(acc[7], hv * t1.w);
            }
            #pragma unroll
            for (int j = 0; j < 8; ++j) sred2[g][j][c] = acc[j];
            __syncthreads();
            {   // combine 8 leaf phases; tid covers all 512 (n,c) pairs
                int n = tid >> 6, cc = tid & 63;
                float v = sred2[0][n][cc];
                #pragma unroll
                for (int p = 1; p < 8; ++p) v = fmaxf(v, sred2[p][n][cc]);
                sagg[n][cc] = v;
            }
            __syncthreads();
            if (tid < 128) {                        // fused f_macro
                int n = tid >> 4, j = tid & 15;
                float a = b3[j];
                #pragma unroll
                for (int cc = 0; cc < 64; ++cc) a += sagg[n][cc] * W3[cc * 16 + j];
                m[(size_t)b * 2048 + (ng * 8 + n) * 16 + j] = fmaxf(a, 0.f);
            }
            __syncthreads();
        }
    }
    __threadfence();
    grid.sync();

    // ============ stage 3: split-K of y = m@W4 (2 units/block) ============
    {
        const int g = tid >> 6, o = tid & 63;
        #pragma unroll
        for (int ub = 0; ub < 2; ++ub) {
            const int u = bid * 2 + ub;
            const int b = u >> 4;                   // 0..31
            const int s = u & 15;                   // k-slice of 128
            if (tid < 128) sm3[tid] = m[(size_t)b * 2048 + s * 128 + tid];
            __syncthreads();
            float a = 0.f;
            #pragma unroll
            for (int k = g; k < 128; k += 8)
                a += sm3[k] * W4[(size_t)(s * 128 + k) * 64 + o];
            sred3[g][o] = a;
            __syncthreads();
            if (tid < 64) {
                float v = 0.f;
                #pragma unroll
                for (int p = 0; p < 8; ++p) v += sred3[p][tid];
                part[((size_t)b * 16 + s) * 64 + tid] = v;
            }
            __syncthreads();
        }
    }
    __threadfence();
    grid.sync();

    // ============ stage 4: combine + BN + final linear (block 0) ==========
    if (bid == 0) {
        #pragma unroll
        for (int idx = tid; idx < 2048; idx += 512) {
            int bb = idx >> 6, o = idx & 63;
            float v = b4[o];
            #pragma unroll
            for (int s = 0; s < 16; ++s) v += part[((size_t)bb * 16 + s) * 64 + o];
            sy[idx] = fmaxf(v, 0.f);
        }
        __syncthreads();
        if (tid < 64) {
            float s1 = 0.f, s2 = 0.f;
            #pragma unroll
            for (int bb = 0; bb < 32; ++bb) {
                float v = sy[bb * 64 + tid];
                s1 += v; s2 += v * v;
            }
            float mean = s1 * (1.f / 32.f);
            float var  = s2 * (1.f / 32.f) - mean * mean;   // biased, torch BN
            sstat[0][tid] = mean;
            sstat[1][tid] = gamma[tid] * rsqrtf(var + 1e-5f);
            sstat[2][tid] = beta[tid];
        }
        __syncthreads();
        if (tid < 320) {
            int bb = tid / 10, q = tid % 10;
            float a = b5[q];
            #pragma unroll
            for (int o = 0; o < 64; ++o)
                a += ((sy[bb * 64 + o] - sstat[0][o]) * sstat[1][o] + sstat[2][o])
                     * W5[o * 10 + q];
            out[bb * 10 + q] = a;
        }
    }
}

// ===================== fallback pipeline (proven, R2) =====================

__global__ __launch_bounds__(256) void k_micro(
    const float* __restrict__ x, const float* __restrict__ W1,
    const float* __restrict__ b1, const float* __restrict__ W2,
    const float* __restrict__ b2, float* __restrict__ h)
{
    const int tid = threadIdx.x;
    const int r = tid >> 6;
    const int c = tid & 63;
    const int row = blockIdx.x * 4 + r;

    __shared__ float sx[4][16];
    __shared__ float sh1[4][32];

    if (c < 16) sx[r][c] = x[row * 16 + c];
    __syncthreads();
    if (c < 32) {
        float a = b1[c];
        #pragma unroll
        for (int i = 0; i < 16; ++i) a += sx[r][i] * W1[i * 32 + c];
        sh1[r][c] = fmaxf(a, 0.f);
    }
    __syncthreads();
    float a = b2[c];
    #pragma unroll
    for (int j = 0; j < 32; ++j) a += sh1[r][j] * W2[j * 64 + c];
    h[(size_t)row * 64 + c] = fmaxf(a, 0.f);
}

__global__ __launch_bounds__(256) void k_agg_macro(
    const float* __restrict__ h, const float* __restrict__ tree,
    const float* __restrict__ W3, const float* __restrict__ b3,
    float* __restrict__ m)
{
    const int ng  = blockIdx.x;
    const int b   = blockIdx.y;
    const int tid = threadIdx.x;
    const int g   = tid >> 6;
    const int c   = tid & 63;

    __shared__ __align__(16) float tl[512][8];
    __shared__ float sred[4][8][64];
    __shared__ float sagg[8][64];

    for (int idx = tid; idx < 4096; idx += 256) {
        int n = idx & 7, l = idx >> 3;
        tl[l][n] = tree[(size_t)(ng * 8 + n) * 512 + l];
    }
    __syncthreads();

    float acc[8];
    #pragma unroll
    for (int j = 0; j < 8; ++j) acc[j] = 0.f;
    const float* hb = h + (size_t)b * 32768 + c;
    #pragma unroll 4
    for (int l = g; l < 512; l += 4) {
        float hv = hb[(size_t)l * 64];
        float4 t0 = *(const float4*)&tl[l][0];
        float4 t1 = *(const float4*)&tl[l][4];
        acc[0] = fmaxf(acc[0], hv * t0.x);
        acc[1] = fmaxf(acc[1], hv * t0.y);
        acc[2] = fmaxf(acc[2], hv * t0.z);
        acc[3] = fmaxf(acc[3], hv * t0.w);
        acc[4] = fmaxf(acc[4], hv * t1.x);
        acc[5] = fmaxf(acc[5], hv * t1.y);
        acc[6] = fmaxf(acc[6], hv * t1.z);
        acc[7] = fmaxf(acc[7], hv * t1.w);
    }
    #pragma unroll
    for (int j = 0; j < 8; ++j) sred[g][j][c] = acc[j];
    __syncthreads();
    for (int idx = tid; idx < 512; idx += 256) {
        int n = idx >> 6, cc = idx & 63;
        sagg[n][cc] = fmaxf(fmaxf(sred[0][n][cc], sred[1][n][cc]),
                            fmaxf(sred[2][n][cc], sred[3][n][cc]));
    }
    __syncthreads();
    if (tid < 128) {
        int n = tid >> 4, j = tid & 15;
        float a = b3[j];
        #pragma unroll
        for (int cc = 0; cc < 64; ++cc) a += sagg[n][cc] * W3[cc * 16 + j];
        m[(size_t)b * 2048 + (ng * 8 + n) * 16 + j] = fmaxf(a, 0.f);
    }
}

__global__ __launch_bounds__(256) void k_fout1_partial(
    const float* __restrict__ m, const float* __restrict__ W4,
    float* __restrict__ part)
{
    const int b   = blockIdx.x;
    const int s   = blockIdx.y;
    const int tid = threadIdx.x;
    const int g = tid >> 6, o = tid & 63;

    __shared__ float sm[256];
    __shared__ float sred[4][64];

    sm[tid] = m[(size_t)b * 2048 + s * 256 + tid];
    __syncthreads();
    float acc = 0.f;
    const float* w = W4 + (size_t)(s * 256) * 64 + o;
    #pragma unroll 8
    for (int k = g; k < 256; k += 4)
        acc += sm[k] * w[(size_t)k * 64];
    sred[g][o] = acc;
    __syncthreads();
    if (tid < 64)
        part[((size_t)b * 8 + s) * 64 + o] =
            sred[0][o] + sred[1][o] + sred[2][o] + sred[3][o];
}

__global__ __launch_bounds__(1024) void k_bn_out(
    const float* __restrict__ part, const float* __restrict__ b4,
    const float* __restrict__ gamma, const float* __restrict__ beta,
    const float* __restrict__ W5, const float* __restrict__ b5,
    float* __restrict__ out)
{
    const int tid = threadIdx.x;
    __shared__ float sy[32 * 64];
    __shared__ float smean[64], sscale[64], sbeta[64];

    #pragma unroll
    for (int idx = tid; idx < 2048; idx += 1024) {
        int b = idx >> 6, o = idx & 63;
        float v = b4[o];
        #pragma unroll
        for (int s = 0; s < 8; ++s) v += part[((size_t)b * 8 + s) * 64 + o];
        sy[idx] = fmaxf(v, 0.f);
    }
    __syncthreads();
    if (tid < 64) {
        float s1 = 0.f, s2 = 0.f;
        #pragma unroll
        for (int b = 0; b < 32; ++b) {
            float v = sy[b * 64 + tid];
            s1 += v; s2 += v * v;
        }
        float mean = s1 * (1.f / 32.f);
        float var  = s2 * (1.f / 32.f) - mean * mean;
        smean[tid]  = mean;
        sscale[tid] = gamma[tid] * rsqrtf(var + 1e-5f);
        sbeta[tid]  = beta[tid];
    }
    __syncthreads();
    if (tid < 320) {
        int b = tid / 10, q = tid % 10;
        float acc = b5[q];
        #pragma unroll
        for (int o = 0; o < 64; ++o)
            acc += ((sy[b * 64 + o] - smean[o]) * sscale[o] + sbeta[o])
                   * W5[o * 10 + q];
        out[b * 10 + q] = acc;
    }
}

extern "C" void kernel_launch(void* const* d_in, const int* in_sizes, int n_in,
                              void* d_out, int out_size, void* d_ws, size_t ws_size,
                              hipStream_t stream) {
    const float* x     = (const float*)d_in[0];
    const float* tree  = (const float*)d_in[1];
    const float* W1    = (const float*)d_in[2];
    const float* b1    = (const float*)d_in[3];
    const float* W2    = (const float*)d_in[4];
    const float* b2    = (const float*)d_in[5];
    const float* W3    = (const float*)d_in[6];
    const float* b3    = (const float*)d_in[7];
    const float* W4    = (const float*)d_in[8];
    const float* b4    = (const float*)d_in[9];
    const float* gamma = (const float*)d_in[10];
    const float* beta  = (const float*)d_in[11];
    const float* W5    = (const float*)d_in[12];
    const float* b5    = (const float*)d_in[13];
    float* out = (float*)d_out;

    float* h    = (float*)d_ws;           // 16384*64 f32 = 4 MB
    float* m    = h + 16384 * 64;         // 32*2048  f32 = 256 KB
    float* part = m + 32 * 2048;          // 32*16*64 f32 = 128 KB

    void* args[] = {
        (void*)&x, (void*)&tree, (void*)&W1, (void*)&b1, (void*)&W2, (void*)&b2,
        (void*)&W3, (void*)&b3, (void*)&W4, (void*)&b4, (void*)&gamma,
        (void*)&beta, (void*)&W5, (void*)&b5, (void*)&out, (void*)&h,
        (void*)&m, (void*)&part
    };
    hipError_t err = hipLaunchCooperativeKernel((const void*)k_fused, dim3(256),
                                                dim3(512), args, 0, stream);
    if (err != hipSuccess) {
        (void)hipGetLastError();          // clear sticky error, use fallback
        k_micro         <<<4096,         256, 0, stream>>>(x, W1, b1, W2, b2, h);
        k_agg_macro     <<<dim3(16, 32), 256, 0, stream>>>(h, tree, W3, b3, m);
        k_fout1_partial <<<dim3(32, 8),  256, 0, stream>>>(m, W4, part);
        k_bn_out        <<<1,           1024, 0, stream>>>(part, b4, gamma, beta, W5, b5, out);
    }
}

// Round 5
// 39.913 us; speedup vs baseline: 5.5573x; 5.5573x over previous
//
#include <hip/hip_runtime.h>

// B=32, L=512, N=128, IN=16, OUT=10
// Two kernels, one boundary:
//  A (grid 8x32, 512 thr): per (ng=16-node group, b): recompute micro-MLP
//    h chunks in LDS (redundancy x8, ~4us total), bitmask max-aggregation,
//    fused f_macro + W4 slice -> part[b][ng][64]
//  B (1 block): y = relu(sum part + b4); BatchNorm (batch stats); @W5+b5

__global__ __launch_bounds__(512, 2) void k_fused_a(
    const float* __restrict__ x, const float* __restrict__ tree,
    const float* __restrict__ W1, const float* __restrict__ b1,
    const float* __restrict__ W2, const float* __restrict__ b2,
    const float* __restrict__ W3, const float* __restrict__ b3,
    const float* __restrict__ W4, float* __restrict__ part)
{
    const int ng   = blockIdx.x;    // 0..7  (nodes ng*16 .. ng*16+15)
    const int b    = blockIdx.y;    // 0..31
    const int tid  = threadIdx.x;
    const int w    = tid >> 6;      // wave 0..7
    const int lane = tid & 63;
    const int cc   = lane & 31;

    // pool regions (floats): X=[64][16] @0, SH1=[64][32] @1024, H=[64][64] @3072
    // epilogue reuses pool[0..8192) as sred[8][16][64]
    __shared__ __align__(16) float pool[8192];
    __shared__ unsigned smask[64];
    __shared__ float sagg[1024];    // [16][64]
    __shared__ float sm[256];       // [16][16]
    __shared__ float spart[512];    // [8][64]

    constexpr int X = 0, SH1 = 1024, H = 3072;

    float w1c[16], w2r[32];
    #pragma unroll
    for (int i = 0; i < 16; ++i) w1c[i] = W1[i * 32 + cc];
    #pragma unroll
    for (int j = 0; j < 32; ++j) w2r[j] = W2[j * 64 + lane];
    const float b1c = b1[cc];
    const float b2c = b2[lane];

    float accv[16];
    #pragma unroll
    for (int n = 0; n < 16; ++n) accv[n] = 0.f;   // h >= 0, 0-init exact

    const float* xb  = x + (size_t)b * (512 * 16);
    const float* tng = tree + (size_t)(ng * 16) * 512;

    for (int ch = 0; ch < 8; ++ch) {
        // ---- stage x chunk (64 rows x 16) + zero masks ----
        if (tid < 64) smask[tid] = 0u;
        pool[X + tid]       = xb[ch * 1024 + tid];
        pool[X + tid + 512] = xb[ch * 1024 + tid + 512];
        __syncthreads();

        // ---- layer1: 512 thr = 8 waves x (2 rows x 32 cols); 4 passes ----
        {
            const int half = lane >> 5;
            #pragma unroll
            for (int q = 0; q < 4; ++q) {
                int row = q * 16 + w * 2 + half;
                float a = b1c;
                #pragma unroll
                for (int i = 0; i < 16; ++i)
                    a += pool[X + row * 16 + i] * w1c[i];
                pool[SH1 + row * 32 + cc] = fmaxf(a, 0.f);
            }
        }
        // ---- build tree bitmasks for this chunk (order-independent OR) ----
        {
            float t0 = tng[(size_t)(2 * w)     * 512 + ch * 64 + lane];
            float t1 = tng[(size_t)(2 * w + 1) * 512 + ch * 64 + lane];
            unsigned bits = (t0 > 0.5f ? (1u << (2 * w)) : 0u)
                          | (t1 > 0.5f ? (2u << (2 * w)) : 0u);
            if (bits) atomicOr(&smask[lane], bits);
        }
        __syncthreads();

        // ---- layer2: row = q*8+w, col = lane ----
        #pragma unroll
        for (int q = 0; q < 8; ++q) {
            int row = q * 8 + w;
            float a = b2c;
            const float4* sp = (const float4*)&pool[SH1 + row * 32];
            #pragma unroll
            for (int jq = 0; jq < 8; ++jq) {
                float4 v = sp[jq];
                a += v.x * w2r[jq * 4 + 0];
                a += v.y * w2r[jq * 4 + 1];
                a += v.z * w2r[jq * 4 + 2];
                a += v.w * w2r[jq * 4 + 3];
            }
            pool[H + row * 64 + lane] = fmaxf(a, 0.f);
        }
        __syncthreads();

        // ---- aggregation: wave w owns leaves w*8..w*8+7 of chunk ----
        #pragma unroll
        for (int j = 0; j < 8; ++j) {
            int l = w * 8 + j;
            int hb = __float_as_int(pool[H + l * 64 + lane]);
            unsigned msk = smask[l];
            #pragma unroll
            for (int n = 0; n < 16; ++n) {
                int sel = (int)(msk << (31 - n)) >> 31;   // 0 or ~0 (bit n)
                accv[n] = fmaxf(accv[n], __int_as_float(hb & sel));
            }
        }
        __syncthreads();    // protect restage of x/sh1/h/masks
    }

    // ---- reduce acc across 8 waves (reuse pool as sred[8][16][64]) ----
    #pragma unroll
    for (int n = 0; n < 16; ++n) pool[w * 1024 + n * 64 + lane] = accv[n];
    __syncthreads();
    #pragma unroll
    for (int p = 0; p < 2; ++p) {
        int nc = p * 512 + tid;                  // (n,c) pair, 0..1023
        float v = pool[nc];
        #pragma unroll
        for (int ww = 1; ww < 8; ++ww) v = fmaxf(v, pool[ww * 1024 + nc]);
        sagg[nc] = v;
    }
    __syncthreads();

    // ---- f_macro: m[n][jj] = relu(b3 + sum_c h_agg*W3) ----
    if (tid < 256) {
        int n = tid >> 4, jj = tid & 15;
        float a = b3[jj];
        #pragma unroll
        for (int c2 = 0; c2 < 64; ++c2)
            a += sagg[n * 64 + c2] * W3[c2 * 16 + jj];
        sm[tid] = fmaxf(a, 0.f);                 // sm[n*16+jj]
    }
    __syncthreads();

    // ---- W4 slice: part[b][ng][o] = sum_{kk in ng*256..+256} m*W4 ----
    {
        float a = 0.f;
        const float* w4p = W4 + (size_t)(ng * 256 + w * 32) * 64 + lane;
        #pragma unroll
        for (int k2 = 0; k2 < 32; ++k2)
            a += sm[w * 32 + k2] * w4p[(size_t)k2 * 64];
        spart[w * 64 + lane] = a;
    }
    __syncthreads();
    if (tid < 64) {
        float v = 0.f;
        #pragma unroll
        for (int ww = 0; ww < 8; ++ww) v += spart[ww * 64 + tid];
        part[((size_t)b * 8 + ng) * 64 + tid] = v;
    }
}

// Combine partials + bias + ReLU -> y; BatchNorm (batch stats over B=32);
// final linear (64->10). One block, 1024 threads.
__global__ __launch_bounds__(1024) void k_bn_out(
    const float* __restrict__ part, const float* __restrict__ b4,
    const float* __restrict__ gamma, const float* __restrict__ beta,
    const float* __restrict__ W5, const float* __restrict__ b5,
    float* __restrict__ out)
{
    const int tid = threadIdx.x;
    __shared__ float sy[32 * 64];
    __shared__ float smean[64], sscale[64], sbeta[64];

    #pragma unroll
    for (int idx = tid; idx < 2048; idx += 1024) {
        int b = idx >> 6, o = idx & 63;
        float v = b4[o];
        #pragma unroll
        for (int s = 0; s < 8; ++s) v += part[((size_t)b * 8 + s) * 64 + o];
        sy[idx] = fmaxf(v, 0.f);
    }
    __syncthreads();
    if (tid < 64) {
        float s1 = 0.f, s2 = 0.f;
        #pragma unroll
        for (int b = 0; b < 32; ++b) {
            float v = sy[b * 64 + tid];
            s1 += v; s2 += v * v;
        }
        float mean = s1 * (1.f / 32.f);
        float var  = s2 * (1.f / 32.f) - mean * mean;   // biased, torch BN
        smean[tid]  = mean;
        sscale[tid] = gamma[tid] * rsqrtf(var + 1e-5f);
        sbeta[tid]  = beta[tid];
    }
    __syncthreads();
    if (tid < 320) {
        int b = tid / 10, q = tid % 10;
        float acc = b5[q];
        #pragma unroll
        for (int o = 0; o < 64; ++o)
            acc += ((sy[b * 64 + o] - smean[o]) * sscale[o] + sbeta[o])
                   * W5[o * 10 + q];
        out[b * 10 + q] = acc;
    }
}

extern "C" void kernel_launch(void* const* d_in, const int* in_sizes, int n_in,
                              void* d_out, int out_size, void* d_ws, size_t ws_size,
                              hipStream_t stream) {
    const float* x     = (const float*)d_in[0];
    const float* tree  = (const float*)d_in[1];
    const float* W1    = (const float*)d_in[2];
    const float* b1    = (const float*)d_in[3];
    const float* W2    = (const float*)d_in[4];
    const float* b2    = (const float*)d_in[5];
    const float* W3    = (const float*)d_in[6];
    const float* b3    = (const float*)d_in[7];
    const float* W4    = (const float*)d_in[8];
    const float* b4    = (const float*)d_in[9];
    const float* gamma = (const float*)d_in[10];
    const float* beta  = (const float*)d_in[11];
    const float* W5    = (const float*)d_in[12];
    const float* b5    = (const float*)d_in[13];
    float* out = (float*)d_out;

    float* part = (float*)d_ws;     // 32*8*64 f32 = 64 KB

    k_fused_a<<<dim3(8, 32), 512, 0, stream>>>(x, tree, W1, b1, W2, b2,
                                               W3, b3, W4, part);
    k_bn_out <<<1, 1024, 0, stream>>>(part, b4, gamma, beta, W5, b5, out);
}

// Round 6
// 31.534 us; speedup vs baseline: 7.0340x; 1.2657x over previous
//
#include <hip/hip_runtime.h>

// B=32, L=512, N=128, IN=16, OUT=10
// Three kernels:
//  K1 k_micro   : h = relu(relu(x@W1+b1)@W2+b2) -> global (B*L,64), once.
//  K2 k_agg_part: per (ng=8-node group, b): bitmask max-agg reading h from
//                 global/L2 (3 VALU/pair, ~0 LDS), fused f_macro + W4 slice
//                 -> part[b][16][64]
//  K3 k_bn_out  : y = relu(sum part + b4); BatchNorm (batch stats); @W5+b5

__global__ __launch_bounds__(256) void k_micro(
    const float* __restrict__ x, const float* __restrict__ W1,
    const float* __restrict__ b1, const float* __restrict__ W2,
    const float* __restrict__ b2, float* __restrict__ h)
{
    const int tid = threadIdx.x;
    const int r = tid >> 6;                 // row within block (0..3)
    const int c = tid & 63;                 // channel lane
    const int row = blockIdx.x * 4 + r;

    __shared__ float sx[4][16];
    __shared__ float sh1[4][32];

    if (c < 16) sx[r][c] = x[row * 16 + c];
    __syncthreads();
    if (c < 32) {
        float a = b1[c];
        #pragma unroll
        for (int i = 0; i < 16; ++i) a += sx[r][i] * W1[i * 32 + c];
        sh1[r][c] = fmaxf(a, 0.f);
    }
    __syncthreads();
    float a = b2[c];
    #pragma unroll
    for (int j = 0; j < 32; ++j) a += sh1[r][j] * W2[j * 64 + c];
    h[(size_t)row * 64 + c] = fmaxf(a, 0.f);
}

// grid 512 (1D, XCD-swizzled), 512 threads = 8 waves.
// block -> (ng, b): ng = id>>5; b = (id&7)*4 + ((id>>3)&3)
// so the 16 ng-blocks of batches 4k..4k+3 land on XCD k (id%8 heuristic).
__global__ __launch_bounds__(512, 4) void k_agg_part(
    const float* __restrict__ h,     // [B][512][64]
    const float* __restrict__ tree,  // [128][512]
    const float* __restrict__ W3, const float* __restrict__ b3,
    const float* __restrict__ W4, float* __restrict__ part)
{
    const int id   = blockIdx.x;          // 0..511
    const int b    = (id & 7) * 4 + ((id >> 3) & 3);
    const int ng   = id >> 5;             // 0..15 (nodes ng*8 .. ng*8+7)
    const int tid  = threadIdx.x;
    const int w    = tid >> 6;            // wave 0..7
    const int lane = tid & 63;            // channel

    __shared__ unsigned smask[512];       // per-leaf 8-bit node mask
    __shared__ float sred[8][8][64];      // cross-wave max reduce
    __shared__ float sagg[8][64];
    __shared__ float sm[128];             // m slice for this block
    __shared__ float spart[8][64];

    // ---- build per-leaf masks (each thread owns leaf tid; no atomics) ----
    {
        unsigned bits = 0;
        const float* tp = tree + (size_t)(ng * 8) * 512 + tid;
        #pragma unroll
        for (int n = 0; n < 8; ++n)
            if (tp[(size_t)n * 512] > 0.5f) bits |= (1u << n);
        smask[tid] = bits;
    }
    __syncthreads();

    // ---- max-aggregation: wave w owns leaves w*64..w*64+63 ----
    float acc[8];
    #pragma unroll
    for (int n = 0; n < 8; ++n) acc[n] = 0.f;   // h >= 0, 0-init exact

    const float* hb = h + (size_t)b * 32768 + (size_t)(w * 64) * 64 + lane;
    #pragma unroll 4
    for (int j = 0; j < 64; ++j) {
        int hv = __float_as_int(hb[(size_t)j * 64]);   // coalesced, L2-hot
        unsigned msk = smask[w * 64 + j];              // broadcast b32
        #pragma unroll
        for (int n = 0; n < 8; ++n) {
            int sel = (int)(msk << (31 - n)) >> 31;    // v_bfe_i32: 0 / ~0
            acc[n] = fmaxf(acc[n], __int_as_float(hv & sel));
        }
    }

    #pragma unroll
    for (int n = 0; n < 8; ++n) sred[w][n][lane] = acc[n];
    __syncthreads();

    {   // combine 8 waves: tid covers (n=tid>>6, cc=tid&63)
        float v = sred[0][w][lane];
        #pragma unroll
        for (int ww = 1; ww < 8; ++ww) v = fmaxf(v, sred[ww][w][lane]);
        sagg[w][lane] = v;
    }
    __syncthreads();

    // ---- f_macro: m[n][jj] = relu(b3 + sum_c h_agg*W3) ----
    if (tid < 128) {
        int n = tid >> 4, jj = tid & 15;
        float a = b3[jj];
        #pragma unroll
        for (int c2 = 0; c2 < 64; ++c2)
            a += sagg[n][c2] * W3[c2 * 16 + jj];
        sm[tid] = fmaxf(a, 0.f);             // sm[n*16+jj] = m[ng*128 + ...]
    }
    __syncthreads();

    // ---- W4 slice: part[b][ng][o] = sum_{k in ng*128..+128} m[k]*W4[k][o]
    {
        float a = 0.f;
        const float* w4p = W4 + (size_t)(ng * 128 + w * 16) * 64 + lane;
        #pragma unroll
        for (int k2 = 0; k2 < 16; ++k2)
            a += sm[w * 16 + k2] * w4p[(size_t)k2 * 64];
        spart[w][lane] = a;
    }
    __syncthreads();
    if (tid < 64) {
        float v = 0.f;
        #pragma unroll
        for (int ww = 0; ww < 8; ++ww) v += spart[ww][tid];
        part[((size_t)b * 16 + ng) * 64 + tid] = v;
    }
}

// Combine 16 partials + bias + ReLU -> y; BatchNorm (batch stats over B=32);
// final linear (64->10). One block, 1024 threads.
__global__ __launch_bounds__(1024) void k_bn_out(
    const float* __restrict__ part, const float* __restrict__ b4,
    const float* __restrict__ gamma, const float* __restrict__ beta,
    const float* __restrict__ W5, const float* __restrict__ b5,
    float* __restrict__ out)
{
    const int tid = threadIdx.x;
    __shared__ float sy[32 * 64];
    __shared__ float smean[64], sscale[64], sbeta[64];

    #pragma unroll
    for (int idx = tid; idx < 2048; idx += 1024) {
        int b = idx >> 6, o = idx & 63;
        float v = b4[o];
        #pragma unroll
        for (int s = 0; s < 16; ++s) v += part[((size_t)b * 16 + s) * 64 + o];
        sy[idx] = fmaxf(v, 0.f);
    }
    __syncthreads();
    if (tid < 64) {
        float s1 = 0.f, s2 = 0.f;
        #pragma unroll
        for (int b = 0; b < 32; ++b) {
            float v = sy[b * 64 + tid];
            s1 += v; s2 += v * v;
        }
        float mean = s1 * (1.f / 32.f);
        float var  = s2 * (1.f / 32.f) - mean * mean;   // biased, torch BN
        smean[tid]  = mean;
        sscale[tid] = gamma[tid] * rsqrtf(var + 1e-5f);
        sbeta[tid]  = beta[tid];
    }
    __syncthreads();
    if (tid < 320) {
        int b = tid / 10, q = tid % 10;
        float acc = b5[q];
        #pragma unroll
        for (int o = 0; o < 64; ++o)
            acc += ((sy[b * 64 + o] - smean[o]) * sscale[o] + sbeta[o])
                   * W5[o * 10 + q];
        out[b * 10 + q] = acc;
    }
}

extern "C" void kernel_launch(void* const* d_in, const int* in_sizes, int n_in,
                              void* d_out, int out_size, void* d_ws, size_t ws_size,
                              hipStream_t stream) {
    const float* x     = (const float*)d_in[0];
    const float* tree  = (const float*)d_in[1];
    const float* W1    = (const float*)d_in[2];
    const float* b1    = (const float*)d_in[3];
    const float* W2    = (const float*)d_in[4];
    const float* b2    = (const float*)d_in[5];
    const float* W3    = (const float*)d_in[6];
    const float* b3    = (const float*)d_in[7];
    const float* W4    = (const float*)d_in[8];
    const float* b4    = (const float*)d_in[9];
    const float* gamma = (const float*)d_in[10];
    const float* beta  = (const float*)d_in[11];
    const float* W5    = (const float*)d_in[12];
    const float* b5    = (const float*)d_in[13];
    float* out = (float*)d_out;

    float* h    = (float*)d_ws;           // 16384*64 f32 = 4 MB
    float* part = h + 16384 * 64;         // 32*16*64 f32 = 128 KB

    k_micro   <<<4096, 256, 0, stream>>>(x, W1, b1, W2, b2, h);
    k_agg_part<<<512,  512, 0, stream>>>(h, tree, W3, b3, W4, part);
    k_bn_out  <<<1,   1024, 0, stream>>>(part, b4, gamma, beta, W5, b5, out);
}